// Round 1
// baseline (240.648 us; speedup 1.0000x reference)
//
#include <hip/hip_runtime.h>

// Aggregator: B=8192, H=10, N=25, F=128, D=256 (half=128). Rows = B*H = 81920.
// out[row][0:128]   = relu(x_self[row]        @ w_self  + bias[0:128])
// out[row][128:256] = relu(mean_n(x_neigh[row]) @ w_neigh + bias[128:256])

#define RPB 16  // rows per block

__global__ __launch_bounds__(256, 4) void agg_fused_kernel(
    const float* __restrict__ x_self,   // [rows][128]
    const float* __restrict__ x_neigh,  // [rows][25][128]
    const float* __restrict__ w_neigh,  // [128][128]
    const float* __restrict__ w_self,   // [128][128]
    const float* __restrict__ bias,     // [256]
    float* __restrict__ out,            // [rows][256]
    int rows)
{
    __shared__ float xs[RPB][128];
    __shared__ float ag[RPB][128];

    const int tid  = threadIdx.x;
    const int row0 = blockIdx.x * RPB;

    // ---- Phase 1: stage x_self rows and neighbor-mean rows into LDS ----
    // Item space: RPB rows * 32 float4-cols = 512 items; 256 threads * 2 items.
    const float4* xs4 = (const float4*)x_self;
    const float4* xn4 = (const float4*)x_neigh;
    #pragma unroll
    for (int it = 0; it < 2; ++it) {
        const int item = tid + it * 256;
        const int r = item >> 5;      // 0..15
        const int v = item & 31;      // float4 column
        const size_t row = (size_t)(row0 + r);

        float4 s = xs4[row * 32 + v];
        *(float4*)&xs[r][v * 4] = s;

        float4 acc = make_float4(0.f, 0.f, 0.f, 0.f);
        const size_t base = row * 800 + v;   // float4 units; row stride 25*32=800
        #pragma unroll
        for (int n = 0; n < 25; ++n) {
            float4 t = xn4[base + (size_t)n * 32];
            acc.x += t.x; acc.y += t.y; acc.z += t.z; acc.w += t.w;
        }
        const float inv = 1.0f / 25.0f;
        acc.x *= inv; acc.y *= inv; acc.z *= inv; acc.w *= inv;
        *(float4*)&ag[r][v * 4] = acc;
    }
    __syncthreads();

    // ---- Phase 2: projections ----
    // thread t: output column (t & 127), half (t >> 7): 0 = self, 1 = neigh.
    // sel is wave-uniform (waves 0,1 -> self; waves 2,3 -> neigh).
    const int col = tid & 127;
    const int sel = tid >> 7;
    const float* __restrict__ w = sel ? w_neigh : w_self;
    const float (*vec)[128] = sel ? ag : xs;

    float acc[RPB];
    #pragma unroll
    for (int r = 0; r < RPB; ++r) acc[r] = 0.f;

    for (int f4 = 0; f4 < 32; ++f4) {
        // 4 weight scalars per iteration; coalesced across the wave (col = lane).
        const float w0 = w[(f4 * 4 + 0) * 128 + col];
        const float w1 = w[(f4 * 4 + 1) * 128 + col];
        const float w2 = w[(f4 * 4 + 2) * 128 + col];
        const float w3 = w[(f4 * 4 + 3) * 128 + col];
        #pragma unroll
        for (int r = 0; r < RPB; ++r) {
            float4 v = *(const float4*)&vec[r][f4 * 4];  // wave-uniform broadcast
            acc[r] = fmaf(v.x, w0, acc[r]);
            acc[r] = fmaf(v.y, w1, acc[r]);
            acc[r] = fmaf(v.z, w2, acc[r]);
            acc[r] = fmaf(v.w, w3, acc[r]);
        }
    }

    const float b = bias[sel * 128 + col];
    #pragma unroll
    for (int r = 0; r < RPB; ++r) {
        const float o = fmaxf(acc[r] + b, 0.f);
        out[(size_t)(row0 + r) * 256 + sel * 128 + col] = o;
    }
}

extern "C" void kernel_launch(void* const* d_in, const int* in_sizes, int n_in,
                              void* d_out, int out_size, void* d_ws, size_t ws_size,
                              hipStream_t stream) {
    const float* x_self  = (const float*)d_in[0];
    const float* x_neigh = (const float*)d_in[1];
    const float* w_neigh = (const float*)d_in[2];
    const float* w_self  = (const float*)d_in[3];
    const float* bias    = (const float*)d_in[4];
    float* out = (float*)d_out;

    const int rows = in_sizes[0] / 128;        // B*H = 81920
    const int blocks = (rows + RPB - 1) / RPB; // 5120

    agg_fused_kernel<<<blocks, 256, 0, stream>>>(
        x_self, x_neigh, w_neigh, w_self, bias, out, rows);
}